// Round 1
// baseline (232.394 us; speedup 1.0000x reference)
//
#include <hip/hip_runtime.h>
#include <stdint.h>

// Problem constants
#define NTOT 8192   // B*(1+NPOS)
#define DD   128    // feature dim
#define BB   2048   // batch
#define NX   6144   // NPOS*B rows of x
// loss_neg subsample correction: log(4096/8191)
#define LOG_SUB_FRAC (-0.6930251f)
#define SQRT10 3.16227766017f
#define NBLK 2080   // 64*65/2 upper-tri tiles

typedef __attribute__((ext_vector_type(4))) float floatx4;  // MFMA C/D
typedef __attribute__((ext_vector_type(4))) int   intx4;
typedef __attribute__((ext_vector_type(8))) int   intx8;    // 32 B fp8 frag

// DPP add: s + permuted(s). Row = 16 lanes on CDNA.
template <int CTRL>
__device__ __forceinline__ float dpp_add(float s) {
  return s + __int_as_float(
      __builtin_amdgcn_update_dpp(0, __float_as_int(s), CTRL, 0xF, 0xF, true));
}
// Sum across a 16-lane row (result in all 16 lanes): xor1, xor2, ror4, ror8.
__device__ __forceinline__ float row16_sum(float s) {
  s = dpp_add<0xB1>(s);   // quad_perm [1,0,3,2]
  s = dpp_add<0x4E>(s);   // quad_perm [2,3,0,1]
  s = dpp_add<0x124>(s);  // row_ror:4
  s = dpp_add<0x128>(s);  // row_ror:8
  return s;
}

// K1: L2-normalize rows of z = [x ; x_pair], scale by sqrt(10) (folds 1/TEMP
// into the MFMA so sim accumulates 10*cos directly) -> fp8 e4m3 (OCP).
// Fused positive dots (pure f32, unscaled). One wave per row.
// Zero-inits rowtotals[8192] and the K2 completion counter (stream-ordered).
__global__ __launch_bounds__(256) void mp_norm(const float* __restrict__ x,
                                               const float* __restrict__ xp,
                                               uint8_t* __restrict__ znb8,
                                               float* __restrict__ pos,
                                               float* __restrict__ rowtotals,
                                               uint32_t* __restrict__ cnt) {
  const int z = blockIdx.x * 256 + threadIdx.x;
  if (z < NTOT) rowtotals[z] = 0.f;
  if (z == 0) *cnt = 0u;

  const int row  = blockIdx.x * 4 + (threadIdx.x >> 6);
  const int lane = threadIdx.x & 63;
  const bool isx = row < NX;
  const float* src = isx ? (x + (size_t)row * DD) : (xp + (size_t)(row - NX) * DD);
  float2 v = ((const float2*)src)[lane];
  float ss = v.x * v.x + v.y * v.y;

  float ssp = 0.f, d = 0.f;
  if (isx) {
    const int b = row & (BB - 1);
    float2 p = ((const float2*)(xp + (size_t)b * DD))[lane];
    ssp = p.x * p.x + p.y * p.y;
    d = v.x * p.x + v.y * p.y;
  }
  // wave-wide sums (all lanes get result)
  ss  = row16_sum(ss);  ss  += __shfl_xor(ss, 16, 64);  ss  += __shfl_xor(ss, 32, 64);
  if (isx) {
    ssp = row16_sum(ssp); ssp += __shfl_xor(ssp, 16, 64); ssp += __shfl_xor(ssp, 32, 64);
    d   = row16_sum(d);   d   += __shfl_xor(d, 16, 64);   d   += __shfl_xor(d, 32, 64);
  }
  const float rn = rsqrtf(ss);           // pure normalizer (for pos)
  const float rns = rn * SQRT10;         // scaled for znb8
  const int pk = __builtin_amdgcn_cvt_pk_fp8_f32(v.x * rns, v.y * rns, 0, false);
  *(uint16_t*)(znb8 + (size_t)row * DD + lane * 2) = (uint16_t)(pk & 0xffff);
  if (isx && lane == 0) pos[row] = d * rn * rsqrtf(ssp);
}

// K2: upper-triangle 128x128 tiles of 10*sim = Zs*Zs^T via MX-scaled fp8 MFMA
// (mfma_scale_f32_16x16x128_f8f6f4, fmt=e4m3, unit scales 0x7F -> x1.0).
// NO LDS staging: znb8 is 1 MB -> fully L2-resident per XCD, so fragments are
// loaded straight from global (common-mistake #7: don't stage L2-fit data).
// This removes the vmcnt(0)+barrier drain before the MFMAs and all swizzle
// address math. Per block: 64 KB of L2 reads (133 MB aggregate ~ 3.9 us).
// Epilogue: exp(acc) row+col sums -> atomicAdd rowtotals. Fused tail: the
// last block to finish (device-scope counter) computes the final scalar.
__global__ __launch_bounds__(256, 4) void mp_simexp(const uint8_t* __restrict__ znb8,
                                                    float* __restrict__ rowtotals,
                                                    const float* __restrict__ pos,
                                                    float* __restrict__ out,
                                                    uint32_t* __restrict__ cnt) {
  __shared__ float rl[4], rp[4];
  __shared__ int lastflag;

  // Triangular decode: block t -> (bi, bj), bi <= bj.
  const int t = blockIdx.x;
  int bi = (int)((129.0f - sqrtf(16641.0f - 8.0f * (float)t)) * 0.5f);
  #define FCUM(r) ((r) * 64 - ((r) * ((r) - 1)) / 2)
  while (bi > 0 && FCUM(bi) > t) --bi;
  while (FCUM(bi + 1) <= t) ++bi;
  const int bj = bi + (t - FCUM(bi));
  const bool diag = (bi == bj);

  const int tid  = threadIdx.x;
  const int wave = tid >> 6, lane = tid & 63;
  const int lhi = lane >> 4, llo = lane & 15;
  const int wr = wave >> 1, wc = wave & 1;

  // Wave (wr,wc) computes the 64x64 subtile A[wr*64..+64) x B[wc*64..+64).
  const uint8_t* gA = znb8 + (size_t)(bi * 128 + wr * 64) * DD;
  const uint8_t* gB = znb8 + (size_t)(bj * 128 + wc * 64) * DD;

  // Fragments direct from L2. Frag: lane(llo=row, lhi): 32 contiguous K bytes
  // at byte offset lhi*32 of the 128-B row. (Identical logical bytes to the
  // old LDS path: its source-swizzle and read-swizzle composed to identity.)
  intx8 bfrag[4];
  #pragma unroll
  for (int c = 0; c < 4; ++c) {
    const uint8_t* base = gB + (c * 16 + llo) * DD + lhi * 32;
    intx4 lo = *(const intx4*)(base);
    intx4 hi = *(const intx4*)(base + 16);
    bfrag[c] = intx8{lo.x, lo.y, lo.z, lo.w, hi.x, hi.y, hi.z, hi.w};
  }
  floatx4 acc[4][4] = {};
  #pragma unroll
  for (int r = 0; r < 4; ++r) {
    const uint8_t* base = gA + (r * 16 + llo) * DD + lhi * 32;
    intx4 lo = *(const intx4*)(base);
    intx4 hi = *(const intx4*)(base + 16);
    intx8 afrag = intx8{lo.x, lo.y, lo.z, lo.w, hi.x, hi.y, hi.z, hi.w};
    #pragma unroll
    for (int c = 0; c < 4; ++c)
      acc[r][c] = __builtin_amdgcn_mfma_scale_f32_16x16x128_f8f6f4(
          afrag, bfrag[c], acc[r][c], 0, 0, 0, 0x7F7F7F7F, 0, 0x7F7F7F7F);
  }

  // Epilogue: e = exp(acc) (acc is already 10*cos); diag masked on the 64
  // diagonal blocks only (uniform branch). Row sums + col sums.
  // C/D layout: col = lane&15, row = (lane>>4)*4 + reg.
  float rowacc[4][4];
  #pragma unroll
  for (int r = 0; r < 4; ++r)
    #pragma unroll
    for (int j = 0; j < 4; ++j) rowacc[r][j] = 0.f;
  float colacc[4] = {0.f, 0.f, 0.f, 0.f};

  if (diag) {
    #pragma unroll
    for (int r = 0; r < 4; ++r) {
      #pragma unroll
      for (int c = 0; c < 4; ++c) {
        const int col = wc * 64 + c * 16 + llo;
        #pragma unroll
        for (int j = 0; j < 4; ++j) {
          const int row = wr * 64 + r * 16 + lhi * 4 + j;
          float e = __expf(acc[r][c][j]);
          if (row == col) e = 0.f;
          rowacc[r][j] += e;
          colacc[c] += e;
        }
      }
    }
  } else {
    #pragma unroll
    for (int r = 0; r < 4; ++r) {
      #pragma unroll
      for (int c = 0; c < 4; ++c) {
        #pragma unroll
        for (int j = 0; j < 4; ++j) {
          float e = __expf(acc[r][c][j]);
          rowacc[r][j] += e;
          colacc[c] += e;
        }
      }
    }
  }

  // Row sums: DPP-reduce across llo; lane llo==j issues the atomic for reg j.
  float* rowdst = rowtotals + bi * 128 + wr * 64;
  #pragma unroll
  for (int r = 0; r < 4; ++r) {
    #pragma unroll
    for (int j = 0; j < 4; ++j) {
      float s = row16_sum(rowacc[r][j]);
      if (llo == j) atomicAdd(&rowdst[r * 16 + lhi * 4 + j], s);
    }
  }
  // Col sums (skip on diag: rows already fully counted by rowsums there).
  if (!diag) {
    float* coldst = rowtotals + bj * 128 + wc * 64;
    #pragma unroll
    for (int c = 0; c < 4; ++c) {
      float s = colacc[c];
      s += __shfl_xor(s, 16, 64);
      s += __shfl_xor(s, 32, 64);
      if (lhi == 0) atomicAdd(&coldst[c * 16 + llo], s);  // 16 lanes, coalesced
    }
  }

  // ---- fused tail: last block to finish computes the final scalar ----
  __threadfence();       // make this block's rowtotal atomics globally visible
  __syncthreads();       // order all threads' fences before the counter bump
  if (tid == 0) {
    uint32_t old = __hip_atomic_fetch_add(cnt, 1u, __ATOMIC_ACQ_REL,
                                          __HIP_MEMORY_SCOPE_AGENT);
    lastflag = (old == NBLK - 1);
  }
  __syncthreads();
  if (!lastflag) return;

  // 256 threads: 32 row-logs + 24 pos reads each. Agent-scope atomic loads of
  // rowtotals read the coherent point (rows were only ever touched by atomics).
  float l = 0.f;
  #pragma unroll
  for (int k = 0; k < 32; ++k) {
    float v = __hip_atomic_load(&rowtotals[k * 256 + tid], __ATOMIC_RELAXED,
                                __HIP_MEMORY_SCOPE_AGENT);
    l += logf(v);
  }
  float p = 0.f;
  #pragma unroll
  for (int k = 0; k < 24; ++k) p += pos[k * 256 + tid];
  #pragma unroll
  for (int m = 1; m < 64; m <<= 1) {
    l += __shfl_xor(l, m, 64);
    p += __shfl_xor(p, m, 64);
  }
  if ((tid & 63) == 0) { rl[tid >> 6] = l; rp[tid >> 6] = p; }
  __syncthreads();
  if (tid == 0) {
    const float S = rl[0] + rl[1] + rl[2] + rl[3];
    const float P = rp[0] + rp[1] + rp[2] + rp[3];
    const float loss_neg = S / (float)NTOT + LOG_SUB_FRAC;
    const float loss_pos = P * (10.0f / (float)NX);  // WEIGHT * (1/TEMP) / (B*NPOS)
    out[0] = loss_neg - loss_pos;
  }
}

extern "C" void kernel_launch(void* const* d_in, const int* in_sizes, int n_in,
                              void* d_out, int out_size, void* d_ws, size_t ws_size,
                              hipStream_t stream) {
  const float* x  = (const float*)d_in[0];   // [6144, 128] f32
  const float* xp = (const float*)d_in[1];   // [2048, 128] f32
  float* out = (float*)d_out;                // scalar f32

  char* ws = (char*)d_ws;
  uint8_t* znb8    = (uint8_t*)ws;                              // 1 MB
  float* pos       = (float*)(ws + (1u << 20));                 // 24 KB
  float* rowtotals = (float*)(ws + (1u << 20) + (32u << 10));   // 32 KB
  uint32_t* cnt    = (uint32_t*)(ws + (1u << 20) + (64u << 10));

  mp_norm<<<NTOT / 4, 256, 0, stream>>>(x, xp, znb8, pos, rowtotals, cnt);
  mp_simexp<<<NBLK, 256, 0, stream>>>(znb8, rowtotals, pos, out, cnt);
}

// Round 2
// 99.782 us; speedup vs baseline: 2.3290x; 2.3290x over previous
//
#include <hip/hip_runtime.h>
#include <stdint.h>

// Problem constants
#define NTOT 8192   // B*(1+NPOS)
#define DD   128    // feature dim
#define BB   2048   // batch
#define NX   6144   // NPOS*B rows of x
// loss_neg subsample correction: log(4096/8191)
#define LOG_SUB_FRAC (-0.6930251f)
#define SQRT10 3.16227766017f
#define NBLK 2080   // 64*65/2 upper-tri tiles

typedef __attribute__((ext_vector_type(4))) float floatx4;  // MFMA C/D
typedef __attribute__((ext_vector_type(4))) int   intx4;
typedef __attribute__((ext_vector_type(8))) int   intx8;    // 32 B fp8 frag

// DPP add: s + permuted(s). Row = 16 lanes on CDNA.
template <int CTRL>
__device__ __forceinline__ float dpp_add(float s) {
  return s + __int_as_float(
      __builtin_amdgcn_update_dpp(0, __float_as_int(s), CTRL, 0xF, 0xF, true));
}
// Sum across a 16-lane row (result in all 16 lanes): xor1, xor2, ror4, ror8.
__device__ __forceinline__ float row16_sum(float s) {
  s = dpp_add<0xB1>(s);   // quad_perm [1,0,3,2]
  s = dpp_add<0x4E>(s);   // quad_perm [2,3,0,1]
  s = dpp_add<0x124>(s);  // row_ror:4
  s = dpp_add<0x128>(s);  // row_ror:8
  return s;
}

// K1: L2-normalize rows of z = [x ; x_pair], scale by sqrt(10) (folds 1/TEMP
// into the MFMA so sim accumulates 10*cos directly) -> fp8 e4m3 (OCP).
// Fused positive dots (pure f32, unscaled). One wave per row.
// Zero-inits rowtotals[8192] (atomic target for K2) — stream-ordered.
__global__ __launch_bounds__(256) void mp_norm(const float* __restrict__ x,
                                               const float* __restrict__ xp,
                                               uint8_t* __restrict__ znb8,
                                               float* __restrict__ pos,
                                               float* __restrict__ rowtotals) {
  const int z = blockIdx.x * 256 + threadIdx.x;
  if (z < NTOT) rowtotals[z] = 0.f;

  const int row  = blockIdx.x * 4 + (threadIdx.x >> 6);
  const int lane = threadIdx.x & 63;
  const bool isx = row < NX;
  const float* src = isx ? (x + (size_t)row * DD) : (xp + (size_t)(row - NX) * DD);
  float2 v = ((const float2*)src)[lane];
  float ss = v.x * v.x + v.y * v.y;

  float ssp = 0.f, d = 0.f;
  if (isx) {
    const int b = row & (BB - 1);
    float2 p = ((const float2*)(xp + (size_t)b * DD))[lane];
    ssp = p.x * p.x + p.y * p.y;
    d = v.x * p.x + v.y * p.y;
  }
  // wave-wide sums (all lanes get result)
  ss  = row16_sum(ss);  ss  += __shfl_xor(ss, 16, 64);  ss  += __shfl_xor(ss, 32, 64);
  if (isx) {
    ssp = row16_sum(ssp); ssp += __shfl_xor(ssp, 16, 64); ssp += __shfl_xor(ssp, 32, 64);
    d   = row16_sum(d);   d   += __shfl_xor(d, 16, 64);   d   += __shfl_xor(d, 32, 64);
  }
  const float rn = rsqrtf(ss);           // pure normalizer (for pos)
  const float rns = rn * SQRT10;         // scaled for znb8
  const int pk = __builtin_amdgcn_cvt_pk_fp8_f32(v.x * rns, v.y * rns, 0, false);
  *(uint16_t*)(znb8 + (size_t)row * DD + lane * 2) = (uint16_t)(pk & 0xffff);
  if (isx && lane == 0) pos[row] = d * rn * rsqrtf(ssp);
}

// K2: upper-triangle 128x128 tiles of 10*sim = Zs*Zs^T via MX-scaled fp8 MFMA
// (mfma_scale_f32_16x16x128_f8f6f4, fmt=e4m3, unit scales 0x7F -> x1.0).
// NO LDS staging: znb8 is 1 MB -> fully L2-resident per XCD, so fragments are
// loaded straight from global (common-mistake #7: don't stage L2-fit data).
// Removes the vmcnt(0)+barrier drain before the MFMAs and all swizzle math.
// Per block: 64 KB of L2 reads (133 MB aggregate ~ 4 us at 34 TB/s).
// Epilogue: exp(acc) row+col sums -> atomicAdd rowtotals.
// NO device fences on the hot path (R1 post-mortem: 2080 per-block
// __threadfence = 10.4 MB of L2 writebacks, kernel 180 us, MfmaUtil 0.9%.
// Coherence with K3 comes from the stream-ordered kernel boundary).
__global__ __launch_bounds__(256, 4) void mp_simexp(const uint8_t* __restrict__ znb8,
                                                    float* __restrict__ rowtotals) {
  // Triangular decode: block t -> (bi, bj), bi <= bj.
  const int t = blockIdx.x;
  int bi = (int)((129.0f - sqrtf(16641.0f - 8.0f * (float)t)) * 0.5f);
  #define FCUM(r) ((r) * 64 - ((r) * ((r) - 1)) / 2)
  while (bi > 0 && FCUM(bi) > t) --bi;
  while (FCUM(bi + 1) <= t) ++bi;
  const int bj = bi + (t - FCUM(bi));
  const bool diag = (bi == bj);

  const int tid  = threadIdx.x;
  const int wave = tid >> 6, lane = tid & 63;
  const int lhi = lane >> 4, llo = lane & 15;
  const int wr = wave >> 1, wc = wave & 1;

  // Wave (wr,wc) computes the 64x64 subtile A[wr*64..+64) x B[wc*64..+64).
  const uint8_t* gA = znb8 + (size_t)(bi * 128 + wr * 64) * DD;
  const uint8_t* gB = znb8 + (size_t)(bj * 128 + wc * 64) * DD;

  // Fragments direct from L2. Frag: lane(llo=row, lhi): 32 contiguous K bytes
  // at byte offset lhi*32 of the 128-B row. A wave's two intx4 loads cover a
  // contiguous 2 KB (16 rows x 128 B) segment -> fully coalesced.
  intx8 bfrag[4];
  #pragma unroll
  for (int c = 0; c < 4; ++c) {
    const uint8_t* base = gB + (c * 16 + llo) * DD + lhi * 32;
    intx4 lo = *(const intx4*)(base);
    intx4 hi = *(const intx4*)(base + 16);
    bfrag[c] = intx8{lo.x, lo.y, lo.z, lo.w, hi.x, hi.y, hi.z, hi.w};
  }
  floatx4 acc[4][4] = {};
  #pragma unroll
  for (int r = 0; r < 4; ++r) {
    const uint8_t* base = gA + (r * 16 + llo) * DD + lhi * 32;
    intx4 lo = *(const intx4*)(base);
    intx4 hi = *(const intx4*)(base + 16);
    intx8 afrag = intx8{lo.x, lo.y, lo.z, lo.w, hi.x, hi.y, hi.z, hi.w};
    #pragma unroll
    for (int c = 0; c < 4; ++c)
      acc[r][c] = __builtin_amdgcn_mfma_scale_f32_16x16x128_f8f6f4(
          afrag, bfrag[c], acc[r][c], 0, 0, 0, 0x7F7F7F7F, 0, 0x7F7F7F7F);
  }

  // Epilogue: e = exp(acc) (acc is already 10*cos); diag masked on the 64
  // diagonal blocks only (uniform branch). Row sums + col sums.
  // C/D layout: col = lane&15, row = (lane>>4)*4 + reg.
  float rowacc[4][4];
  #pragma unroll
  for (int r = 0; r < 4; ++r)
    #pragma unroll
    for (int j = 0; j < 4; ++j) rowacc[r][j] = 0.f;
  float colacc[4] = {0.f, 0.f, 0.f, 0.f};

  if (diag) {
    #pragma unroll
    for (int r = 0; r < 4; ++r) {
      #pragma unroll
      for (int c = 0; c < 4; ++c) {
        const int col = wc * 64 + c * 16 + llo;
        #pragma unroll
        for (int j = 0; j < 4; ++j) {
          const int row = wr * 64 + r * 16 + lhi * 4 + j;
          float e = __expf(acc[r][c][j]);
          if (row == col) e = 0.f;
          rowacc[r][j] += e;
          colacc[c] += e;
        }
      }
    }
  } else {
    #pragma unroll
    for (int r = 0; r < 4; ++r) {
      #pragma unroll
      for (int c = 0; c < 4; ++c) {
        #pragma unroll
        for (int j = 0; j < 4; ++j) {
          float e = __expf(acc[r][c][j]);
          rowacc[r][j] += e;
          colacc[c] += e;
        }
      }
    }
  }

  // Row sums: DPP-reduce across llo; lane llo==j issues the atomic for reg j.
  float* rowdst = rowtotals + bi * 128 + wr * 64;
  #pragma unroll
  for (int r = 0; r < 4; ++r) {
    #pragma unroll
    for (int j = 0; j < 4; ++j) {
      float s = row16_sum(rowacc[r][j]);
      if (llo == j) atomicAdd(&rowdst[r * 16 + lhi * 4 + j], s);
    }
  }
  // Col sums (skip on diag: rows already fully counted by rowsums there).
  if (!diag) {
    float* coldst = rowtotals + bj * 128 + wc * 64;
    #pragma unroll
    for (int c = 0; c < 4; ++c) {
      float s = colacc[c];
      s += __shfl_xor(s, 16, 64);
      s += __shfl_xor(s, 32, 64);
      if (lhi == 0) atomicAdd(&coldst[c * 16 + llo], s);  // 16 lanes, coalesced
    }
  }
}

// K3: fused tail — per-row log + mean, pos-sum, final scalar. One block.
__global__ __launch_bounds__(1024) void mp_tail(const float* __restrict__ rowtotals,
                                                const float* __restrict__ pos,
                                                float* __restrict__ out) {
  const int tid = threadIdx.x;
  float l = 0.f;
  #pragma unroll
  for (int k = 0; k < 8; ++k) l += logf(rowtotals[k * 1024 + tid]);
  float p = 0.f;
  for (int t = tid; t < NX; t += 1024) p += pos[t];
  #pragma unroll
  for (int m = 1; m < 64; m <<= 1) {
    l += __shfl_xor(l, m, 64);
    p += __shfl_xor(p, m, 64);
  }
  __shared__ float rl[16], rp[16];
  if ((tid & 63) == 0) { rl[tid >> 6] = l; rp[tid >> 6] = p; }
  __syncthreads();
  if (tid == 0) {
    float S = 0.f, P = 0.f;
    #pragma unroll
    for (int w = 0; w < 16; ++w) { S += rl[w]; P += rp[w]; }
    const float loss_neg = S / (float)NTOT + LOG_SUB_FRAC;
    const float loss_pos = P * (10.0f / (float)NX);  // WEIGHT * (1/TEMP) / (B*NPOS)
    out[0] = loss_neg - loss_pos;
  }
}

extern "C" void kernel_launch(void* const* d_in, const int* in_sizes, int n_in,
                              void* d_out, int out_size, void* d_ws, size_t ws_size,
                              hipStream_t stream) {
  const float* x  = (const float*)d_in[0];   // [6144, 128] f32
  const float* xp = (const float*)d_in[1];   // [2048, 128] f32
  float* out = (float*)d_out;                // scalar f32

  char* ws = (char*)d_ws;
  uint8_t* znb8    = (uint8_t*)ws;                              // 1 MB
  float* pos       = (float*)(ws + (1u << 20));                 // 24 KB
  float* rowtotals = (float*)(ws + (1u << 20) + (32u << 10));   // 32 KB

  mp_norm<<<NTOT / 4, 256, 0, stream>>>(x, xp, znb8, pos, rowtotals);
  mp_simexp<<<NBLK, 256, 0, stream>>>(znb8, rowtotals);
  mp_tail<<<1, 1024, 0, stream>>>(rowtotals, pos, out);
}